// Round 7
// baseline (138.809 us; speedup 1.0000x reference)
//
#include <hip/hip_runtime.h>
#include <hip/hip_bf16.h>

#define LSEQ 1024
#define NB   2
#define NH   8
#define DD   64
#define DMOD 768

using bf16x8 = __attribute__((ext_vector_type(8))) short;
using f32x4  = __attribute__((ext_vector_type(4))) float;

__device__ inline unsigned short f2bf(float f) {
    union { float f; unsigned u; } v; v.f = f;
    unsigned r = v.u + 0x7FFFu + ((v.u >> 16) & 1u);
    return (unsigned short)(r >> 16);
}
// packed fp32x2 -> bf16x2 (RNE), lowers to v_cvt_pk_bf16_f32 on gfx950
__device__ inline unsigned pk2bf(float a, float b) {
    union { __hip_bfloat162 h; unsigned u; } c;
    c.h = __float22bfloat162_rn(make_float2(a, b));
    return c.u;
}

// ---------------------------------------------------------------------------
// fused QKV projection GEMM reading fp32 x / Wq / Wk / Wv directly
// (bf16 convert fused into LDS staging). Grid (24, 33):
//   y < 32 : GEMM 64x64 tiles, [2048x768] @ [1536x768]^T
//            n <  512: Q' = (q + u_bias)/8 -> bf16 [bh][i][d]
//            n < 1024: K  -> bf16 [bh][j][d]
//            else    : V  -> bf16 transposed [bh][d][j]
//   y == 32: x==0: cls LUT; x==1..8: per-head wsfx (consumed by attn only)
// ---------------------------------------------------------------------------
__global__ __launch_bounds__(256) void gemm_qkv(
    const float* __restrict__ X,
    const float* __restrict__ Wq, const float* __restrict__ Wk,
    const float* __restrict__ Wv,
    const float* __restrict__ u_bias, const float* __restrict__ v_bias,
    const float* __restrict__ w_pos,
    unsigned short* __restrict__ Qb, unsigned short* __restrict__ Kb,
    unsigned short* __restrict__ Vtb,
    float* __restrict__ wsfx, unsigned char* __restrict__ cls_g)
{
    int tid = threadIdx.x;

    if (blockIdx.y == 32) {
        int sb = blockIdx.x;
        if (sb == 0) {
            // cls LUT
            __shared__ float w_s[32];
            __shared__ int cmin_s[1024];
            if (tid < 32) {
                float pr = expf(logf(512.5f) / 32.0f);
                w_s[tid] = powf(pr, (float)(tid + 1));
            }
            __syncthreads();
            for (int d = tid; d < 1024; d += 256) {
                float fd = (float)d;
                int cm = 32;
                for (int c = 31; c >= 0; --c) if (fd <= w_s[c]) cm = c;
                cmin_s[d] = cm;
            }
            __syncthreads();
            for (int d2 = tid; d2 < 2048; d2 += 256) {
                int dd = d2 - 1023;
                int ad = dd < 0 ? -dd : dd; if (ad > 1023) ad = 1023;
                int t = (dd < 0) ? 0 : ((dd == 0) ? 1 : 2);
                cls_g[d2] = (unsigned char)(t * 33 + cmin_s[ad]);
            }
        } else if (sb <= 8) {
            // per-head wsfx[h][n] = (suffix(v.w_pos)-suffix(u.w_pos))/8
            int h = sb - 1;
            __shared__ float vred[4][64];
            __shared__ float ured[4][64];
            __shared__ float wd[64];
            int n = tid & 63, g = tid >> 6;
            float vs = 0.f, us = 0.f;
#pragma unroll
            for (int k = 0; k < 16; ++k) {
                int d = g * 16 + k;
                float wp = w_pos[(h * 64 + d) * 64 + n];
                vs += v_bias[h * 64 + d] * wp;
                us += u_bias[h * 64 + d] * wp;
            }
            vred[g][n] = vs; ured[g][n] = us;
            __syncthreads();
            if (tid < 64) {
                float v4 = vred[0][tid] + vred[1][tid] + vred[2][tid] + vred[3][tid];
                float u4 = ured[0][tid] + ured[1][tid] + ured[2][tid] + ured[3][tid];
                wd[tid] = v4 - u4;
            }
            __syncthreads();
            if (tid < 64) {
                int nn = tid & 31, cb = tid & 32;
                float s = 0.f;
                for (int c = 31; c >= nn; --c) s += wd[cb + c];
                wsfx[h * 64 + tid] = s * 0.125f;
            }
        }
        return;
    }

    __shared__ unsigned short Xs[64][40];
    __shared__ unsigned short Wsm[64][40];
    __shared__ unsigned short Ct[64][72];

    int w = tid >> 6, lane = tid & 63, l15 = lane & 15, q = lane >> 4;
    int M0 = blockIdx.y * 64, N0 = blockIdx.x * 64;
    int rs = tid >> 2, seg = tid & 3;

    const float* Wsrc; int Nrow;
    if (N0 < 512)       { Wsrc = Wq; Nrow = N0; }
    else if (N0 < 1024) { Wsrc = Wk; Nrow = N0 - 512; }
    else                { Wsrc = Wv; Nrow = N0 - 1024; }

    const float* xrow = X    + (size_t)(M0 + rs) * 768 + seg * 8;
    const float* wrow = Wsrc + (size_t)(Nrow + rs) * 768 + seg * 8;

    f32x4 acc[4] = {};
    for (int k0 = 0; k0 < 768; k0 += 32) {
        float4 xa = *(const float4*)(xrow + k0);
        float4 xb = *(const float4*)(xrow + k0 + 4);
        float4 wa = *(const float4*)(wrow + k0);
        float4 wb = *(const float4*)(wrow + k0 + 4);
        uint4 xp, wp;
        xp.x = pk2bf(xa.x, xa.y); xp.y = pk2bf(xa.z, xa.w);
        xp.z = pk2bf(xb.x, xb.y); xp.w = pk2bf(xb.z, xb.w);
        wp.x = pk2bf(wa.x, wa.y); wp.y = pk2bf(wa.z, wa.w);
        wp.z = pk2bf(wb.x, wb.y); wp.w = pk2bf(wb.z, wb.w);
        *(uint4*)&Xs[rs][seg * 8]  = xp;
        *(uint4*)&Wsm[rs][seg * 8] = wp;
        __syncthreads();
        bf16x8 a = *(bf16x8*)&Xs[w * 16 + l15][q * 8];
#pragma unroll
        for (int ct = 0; ct < 4; ++ct) {
            bf16x8 bfr = *(bf16x8*)&Wsm[ct * 16 + l15][q * 8];
            acc[ct] = __builtin_amdgcn_mfma_f32_16x16x32_bf16(a, bfr, acc[ct], 0, 0, 0);
        }
        __syncthreads();
    }

    if (N0 < 1024) {
        int isQ = (N0 < 512);
#pragma unroll
        for (int ct = 0; ct < 4; ++ct) {
            float u0 = isQ ? u_bias[N0 + ct * 16 + l15] : 0.f;
            float sc = isQ ? 0.125f : 1.0f;
#pragma unroll
            for (int r = 0; r < 4; ++r)
                Ct[w * 16 + q * 4 + r][ct * 16 + l15] = f2bf((acc[ct][r] + u0) * sc);
        }
        __syncthreads();
        int Nh = isQ ? N0 : (N0 - 512);
        unsigned short* out = isQ ? Qb : Kb;
        size_t base = ((size_t)((M0 >> 10) * 8 + (Nh >> 6)) * 1024 + (M0 & 1023)) * 64;
#pragma unroll
        for (int it = 0; it < 2; ++it) {
            int idx = tid + it * 256;
            int row = idx >> 3, sg = idx & 7;
            *(uint4*)(out + base + (size_t)row * 64 + sg * 8) = *(uint4*)&Ct[row][sg * 8];
        }
    } else {
#pragma unroll
        for (int ct = 0; ct < 4; ++ct) {
            ushort4 pk;
            pk.x = f2bf(acc[ct][0]); pk.y = f2bf(acc[ct][1]);
            pk.z = f2bf(acc[ct][2]); pk.w = f2bf(acc[ct][3]);
            *(ushort4*)&Ct[ct * 16 + l15][w * 16 + q * 4] = pk;   // [d][j]
        }
        __syncthreads();
        size_t base = ((size_t)((M0 >> 10) * 8 + ((N0 - 1024) >> 6))) * 65536;
        int j0 = M0 & 1023;
#pragma unroll
        for (int it = 0; it < 2; ++it) {
            int idx = tid + it * 256;
            int d = idx >> 3, sg = idx & 7;
            *(uint4*)(Vtb + base + (size_t)d * 1024 + j0 + sg * 8) = *(uint4*)&Ct[d][sg * 8];
        }
    }
}

// ---------------------------------------------------------------------------
// out-projection GEMM: fp32 out [2048][768] = aob[2048][512] @ Wo[768][512]^T + bo
// A = bf16 (ours), B = fp32 Wo converted during staging.
// ---------------------------------------------------------------------------
__global__ __launch_bounds__(256) void gemm_o(
    const unsigned short* __restrict__ X, const float* __restrict__ W,
    const float* __restrict__ bias, float* __restrict__ out)
{
    __shared__ unsigned short Xs[64][40];
    __shared__ unsigned short Wsm[64][40];
    __shared__ float Ctf[64][72];

    int tid = threadIdx.x;
    int w = tid >> 6, lane = tid & 63, l15 = lane & 15, q = lane >> 4;
    int M0 = blockIdx.y * 64, N0 = blockIdx.x * 64;
    int rs = tid >> 2, seg = tid & 3;

    const float* wrow = W + (size_t)(N0 + rs) * 512 + seg * 8;

    f32x4 acc[4] = {};
    for (int k0 = 0; k0 < 512; k0 += 32) {
        uint4 xv = *(const uint4*)(X + (size_t)(M0 + rs) * 512 + k0 + seg * 8);
        float4 wa = *(const float4*)(wrow + k0);
        float4 wb = *(const float4*)(wrow + k0 + 4);
        uint4 wp;
        wp.x = pk2bf(wa.x, wa.y); wp.y = pk2bf(wa.z, wa.w);
        wp.z = pk2bf(wb.x, wb.y); wp.w = pk2bf(wb.z, wb.w);
        *(uint4*)&Xs[rs][seg * 8]  = xv;
        *(uint4*)&Wsm[rs][seg * 8] = wp;
        __syncthreads();
        bf16x8 a = *(bf16x8*)&Xs[w * 16 + l15][q * 8];
#pragma unroll
        for (int ct = 0; ct < 4; ++ct) {
            bf16x8 bfr = *(bf16x8*)&Wsm[ct * 16 + l15][q * 8];
            acc[ct] = __builtin_amdgcn_mfma_f32_16x16x32_bf16(a, bfr, acc[ct], 0, 0, 0);
        }
        __syncthreads();
    }
#pragma unroll
    for (int ct = 0; ct < 4; ++ct) {
        float bv = bias[N0 + ct * 16 + l15];
#pragma unroll
        for (int r = 0; r < 4; ++r)
            Ctf[w * 16 + q * 4 + r][ct * 16 + l15] = acc[ct][r] + bv;
    }
    __syncthreads();
#pragma unroll
    for (int it = 0; it < 4; ++it) {
        int idx = tid + it * 256;
        int row = idx >> 4, sg = idx & 15;
        *(float4*)(out + (size_t)(M0 + row) * 768 + N0 + sg * 4) = *(float4*)&Ctf[row][sg * 4];
    }
}

// ---------------------------------------------------------------------------
// MFMA flash attention with fused qr-bias computation.
// Preamble: stage w_pos[h] fp32->bf16 transposed into LDS; qw = Q'@w_pos^T
//           (2 MFMA/wave); broadcast suffix-scan; biasT in LDS.
// K-loop: 4 waves = 4 j-quarters, no barriers, waves independent.
// ---------------------------------------------------------------------------
__global__ __launch_bounds__(256, 4) void attn_mfma(
    const unsigned short* __restrict__ Qbf,   // [bh][i][d] bf16 ((q+u)/8)
    const unsigned short* __restrict__ Kbf,   // [bh][j][d] bf16
    const unsigned short* __restrict__ Vt,    // [bh][d][j] bf16
    const float* __restrict__ w_pos,          // [h][d][n] fp32
    const float* __restrict__ wsfx,           // [h][64]  (vsfx-usfx)/8
    const unsigned char* __restrict__ cls_g,
    unsigned short* __restrict__ ao)          // [b*1024+i][h*64+d] bf16
{
    __shared__ float biasT[16 * 99];
    __shared__ unsigned char cls[2048];
    __shared__ unsigned short Pl[4][16][76];
    union Ovl {
        struct { unsigned short wptS[64][68]; float qwL[16][68]; } pre;
        struct { float Obuf[4][64][17]; float lbuf[4][16]; } post;
    };
    __shared__ Ovl ovl;

    int tid = threadIdx.x;
    int b = blockIdx.z, h = blockIdx.y, bh = b * 8 + h;
    int i0 = blockIdx.x * 16;
    int w = tid >> 6, lane = tid & 63, l15 = lane & 15, q = lane >> 4;

    for (int idx = tid; idx < 512; idx += 256)
        ((unsigned int*)cls)[idx] = ((const unsigned int*)cls_g)[idx];
    // stage w_pos[h] (fp32 [d][n]) -> bf16 transposed wptS[n][d], padded rows
    {
        const float4* wsrc = (const float4*)(w_pos + h * 4096);
#pragma unroll
        for (int it = 0; it < 4; ++it) {
            int f = tid + it * 256;          // float4 index, 0..1023
            float4 wv = wsrc[f];
            int d = f >> 4, n4 = (f & 15) * 4;
            ovl.pre.wptS[n4 + 0][d] = f2bf(wv.x);
            ovl.pre.wptS[n4 + 1][d] = f2bf(wv.y);
            ovl.pre.wptS[n4 + 2][d] = f2bf(wv.z);
            ovl.pre.wptS[n4 + 3][d] = f2bf(wv.w);
        }
    }

    int ig = i0 + l15;
    const unsigned short* qrow = Qbf + ((size_t)bh * 1024 + ig) * 64;
    bf16x8 qf0 = *(const bf16x8*)(qrow + q * 8);
    bf16x8 qf1 = *(const bf16x8*)(qrow + 32 + q * 8);
    __syncthreads();

    // qw MFMA: wave w covers n = w*16 .. w*16+15
    {
        bf16x8 b0 = *(bf16x8*)&ovl.pre.wptS[w * 16 + l15][q * 8];
        bf16x8 b1 = *(bf16x8*)&ovl.pre.wptS[w * 16 + l15][32 + q * 8];
        f32x4 a = {};
        a = __builtin_amdgcn_mfma_f32_16x16x32_bf16(qf0, b0, a, 0, 0, 0);
        a = __builtin_amdgcn_mfma_f32_16x16x32_bf16(qf1, b1, a, 0, 0, 0);
#pragma unroll
        for (int r = 0; r < 4; ++r)
            ovl.pre.qwL[q * 4 + r][w * 16 + l15] = a[r];
    }
    __syncthreads();

    // suffix-scan halves (fixed 32 iters, broadcast reads) + add wsfx, in-place
    const float* wsh = wsfx + h * 64;
#pragma unroll
    for (int it = 0; it < 4; ++it) {
        int idx = tid + it * 256;
        int il = idx >> 6, n = idx & 63, nn = n & 31, cb = n & 32;
        float run = 0.f, s = 0.f;
#pragma unroll
        for (int c = 31; c >= 0; --c) {
            run += ovl.pre.qwL[il][cb + c];
            if (c == nn) s = run;
        }
        ovl.pre.qwL[il][n] = s + wsh[n];
    }
    __syncthreads();

    for (int idx = tid; idx < 528; idx += 256) {
        int il = idx / 33, c = idx - il * 33;
        float up = 0.f, sp = 0.f;
        if (c < 32) {
            up = ovl.pre.qwL[il][c];
            sp = ovl.pre.qwL[il][32 + c];
        }
        float* bt = biasT + il * 99;
        bt[c]      = up - sp;   // dd < 0
        bt[33 + c] = up;        // dd == 0
        bt[66 + c] = up + sp;   // dd > 0
    }
    __syncthreads();

    const unsigned short* Kbase = Kbf + (size_t)bh * 65536;
    const unsigned short* Vbase = Vt  + (size_t)bh * 65536;
    const float* btrow = biasT + l15 * 99;
    int clsoff = 1023 - ig;

    f32x4 Oacc[4] = {};
    float lsum = 0.f;

    for (int jt = 0; jt < 4; ++jt) {
        int jb = w * 256 + jt * 64;
        f32x4 st[4];
#pragma unroll
        for (int ct = 0; ct < 4; ++ct) {
            const unsigned short* krow = Kbase + (size_t)(jb + ct * 16 + l15) * 64;
            bf16x8 ka0 = *(const bf16x8*)(krow + q * 8);
            bf16x8 ka1 = *(const bf16x8*)(krow + 32 + q * 8);
            f32x4 a = {};
            a = __builtin_amdgcn_mfma_f32_16x16x32_bf16(ka0, qf0, a, 0, 0, 0);
            a = __builtin_amdgcn_mfma_f32_16x16x32_bf16(ka1, qf1, a, 0, 0, 0);
            st[ct] = a;
        }
#pragma unroll
        for (int ct = 0; ct < 4; ++ct) {
            int d2b = jb + ct * 16 + q * 4 + clsoff;
            float pv[4];
#pragma unroll
            for (int r = 0; r < 4; ++r) {
                float s = st[ct][r] + btrow[cls[d2b + r]];
                float p = __expf(s);
                lsum += p;
                pv[r] = p;
            }
            ushort4 pk;
            pk.x = f2bf(pv[0]); pk.y = f2bf(pv[1]);
            pk.z = f2bf(pv[2]); pk.w = f2bf(pv[3]);
            *(ushort4*)&Pl[w][l15][ct * 16 + q * 4] = pk;
        }
#pragma unroll
        for (int ks = 0; ks < 2; ++ks) {
            bf16x8 pb = *(const bf16x8*)&Pl[w][l15][ks * 32 + q * 8];
#pragma unroll
            for (int dt = 0; dt < 4; ++dt) {
                bf16x8 va = *(const bf16x8*)(Vbase + (size_t)(dt * 16 + l15) * 1024
                                             + jb + ks * 32 + q * 8);
                Oacc[dt] = __builtin_amdgcn_mfma_f32_16x16x32_bf16(va, pb, Oacc[dt], 0, 0, 0);
            }
        }
    }

    lsum += __shfl_xor(lsum, 16);
    lsum += __shfl_xor(lsum, 32);

    __syncthreads();   // all preamble/K-loop reads done before overlay reuse
#pragma unroll
    for (int dt = 0; dt < 4; ++dt)
#pragma unroll
        for (int r = 0; r < 4; ++r)
            ovl.post.Obuf[w][dt * 16 + q * 4 + r][l15] = Oacc[dt][r];
    if (lane < 16) ovl.post.lbuf[w][l15] = lsum;
    __syncthreads();

    for (int t2 = tid; t2 < 1024; t2 += 256) {
        int il = t2 >> 6, d = t2 & 63;
        float o = ovl.post.Obuf[0][d][il] + ovl.post.Obuf[1][d][il]
                + ovl.post.Obuf[2][d][il] + ovl.post.Obuf[3][d][il];
        float l = ovl.post.lbuf[0][il] + ovl.post.lbuf[1][il]
                + ovl.post.lbuf[2][il] + ovl.post.lbuf[3][il];
        ao[((size_t)(b * 1024 + i0 + il)) * 512 + h * 64 + d] = f2bf(o / l);
    }
}

// ---------------------------------------------------------------------------
extern "C" void kernel_launch(void* const* d_in, const int* in_sizes, int n_in,
                              void* d_out, int out_size, void* d_ws, size_t ws_size,
                              hipStream_t stream)
{
    const float* x      = (const float*)d_in[0];
    const float* Wq     = (const float*)d_in[1];
    const float* Wk     = (const float*)d_in[2];
    const float* Wv     = (const float*)d_in[3];
    const float* Wo     = (const float*)d_in[4];
    const float* bo     = (const float*)d_in[5];
    const float* u_bias = (const float*)d_in[6];
    const float* v_bias = (const float*)d_in[7];
    const float* w_pos  = (const float*)d_in[8];
    float* out = (float*)d_out;

    char* ws = (char*)d_ws;
    unsigned short* Qbf  = (unsigned short*)ws;            ws += 2097152;
    unsigned short* Kbf  = (unsigned short*)ws;            ws += 2097152;
    unsigned short* Vtb  = (unsigned short*)ws;            ws += 2097152;
    unsigned short* aob  = (unsigned short*)ws;            ws += 2097152;
    float*          wsfx = (float*)ws;                     ws += 2048;
    unsigned char*  clsg = (unsigned char*)ws;             ws += 2048;

    gemm_qkv<<<dim3(24, 33), 256, 0, stream>>>(
        x, Wq, Wk, Wv, u_bias, v_bias, w_pos,
        Qbf, Kbf, Vtb, wsfx, clsg);

    attn_mfma<<<dim3(64, 8, 2), 256, 0, stream>>>(
        Qbf, Kbf, Vtb, w_pos, wsfx, clsg, aob);

    gemm_o<<<dim3(12, 32), 256, 0, stream>>>(aob, Wo, bo, out);
}

// Round 8
// 137.929 us; speedup vs baseline: 1.0064x; 1.0064x over previous
//
#include <hip/hip_runtime.h>
#include <hip/hip_bf16.h>

#define LSEQ 1024
#define NB   2
#define NH   8
#define DD   64
#define DMOD 768

using bf16x8 = __attribute__((ext_vector_type(8))) short;
using f32x4  = __attribute__((ext_vector_type(4))) float;

__device__ inline unsigned short f2bf(float f) {
    union { float f; unsigned u; } v; v.f = f;
    unsigned r = v.u + 0x7FFFu + ((v.u >> 16) & 1u);
    return (unsigned short)(r >> 16);
}
// packed fp32x2 -> bf16x2 (RNE), lowers to v_cvt_pk_bf16_f32 on gfx950
__device__ inline unsigned pk2bf(float a, float b) {
    union { __hip_bfloat162 h; unsigned u; } c;
    c.h = __float22bfloat162_rn(make_float2(a, b));
    return c.u;
}

// ---------------------------------------------------------------------------
// fused QKV projection GEMM, double-buffered LDS + register prefetch.
// Grid (24, 33):
//   y < 32 : 64x64 tiles, [2048x768] @ [1536x768]^T (fp32 in, bf16 MFMA)
//            n <  512: Q' = (q + u_bias)/8 -> bf16 [bh][i][d]
//            n < 1024: K  -> bf16 [bh][j][d]
//            else    : V  -> bf16 transposed [bh][d][j]
//   y == 32: x==0: cls LUT; x==1..8: per-head wsfx
// ---------------------------------------------------------------------------
__global__ __launch_bounds__(256) void gemm_qkv(
    const float* __restrict__ X,
    const float* __restrict__ Wq, const float* __restrict__ Wk,
    const float* __restrict__ Wv,
    const float* __restrict__ u_bias, const float* __restrict__ v_bias,
    const float* __restrict__ w_pos,
    unsigned short* __restrict__ Qb, unsigned short* __restrict__ Kb,
    unsigned short* __restrict__ Vtb,
    float* __restrict__ wsfx, unsigned char* __restrict__ cls_g)
{
    int tid = threadIdx.x;

    if (blockIdx.y == 32) {
        int sb = blockIdx.x;
        if (sb == 0) {
            __shared__ float w_s[32];
            __shared__ int cmin_s[1024];
            if (tid < 32) {
                float pr = expf(logf(512.5f) / 32.0f);
                w_s[tid] = powf(pr, (float)(tid + 1));
            }
            __syncthreads();
            for (int d = tid; d < 1024; d += 256) {
                float fd = (float)d;
                int cm = 32;
                for (int c = 31; c >= 0; --c) if (fd <= w_s[c]) cm = c;
                cmin_s[d] = cm;
            }
            __syncthreads();
            for (int d2 = tid; d2 < 2048; d2 += 256) {
                int dd = d2 - 1023;
                int ad = dd < 0 ? -dd : dd; if (ad > 1023) ad = 1023;
                int t = (dd < 0) ? 0 : ((dd == 0) ? 1 : 2);
                cls_g[d2] = (unsigned char)(t * 33 + cmin_s[ad]);
            }
        } else if (sb <= 8) {
            int h = sb - 1;
            __shared__ float vred[4][64];
            __shared__ float ured[4][64];
            __shared__ float wd[64];
            int n = tid & 63, g = tid >> 6;
            float vs = 0.f, us = 0.f;
#pragma unroll
            for (int k = 0; k < 16; ++k) {
                int d = g * 16 + k;
                float wp = w_pos[(h * 64 + d) * 64 + n];
                vs += v_bias[h * 64 + d] * wp;
                us += u_bias[h * 64 + d] * wp;
            }
            vred[g][n] = vs; ured[g][n] = us;
            __syncthreads();
            if (tid < 64) {
                float v4 = vred[0][tid] + vred[1][tid] + vred[2][tid] + vred[3][tid];
                float u4 = ured[0][tid] + ured[1][tid] + ured[2][tid] + ured[3][tid];
                wd[tid] = v4 - u4;
            }
            __syncthreads();
            if (tid < 64) {
                int nn = tid & 31, cb = tid & 32;
                float s = 0.f;
                for (int c = 31; c >= nn; --c) s += wd[cb + c];
                wsfx[h * 64 + tid] = s * 0.125f;
            }
        }
        return;
    }

    __shared__ unsigned short Xs[2][64][40];
    __shared__ unsigned short Wsm[2][64][40];
    __shared__ unsigned short Ct[64][72];

    int w = tid >> 6, lane = tid & 63, l15 = lane & 15, q = lane >> 4;
    int M0 = blockIdx.y * 64, N0 = blockIdx.x * 64;
    int rs = tid >> 2, seg = tid & 3;

    const float* Wsrc; int Nrow;
    if (N0 < 512)       { Wsrc = Wq; Nrow = N0; }
    else if (N0 < 1024) { Wsrc = Wk; Nrow = N0 - 512; }
    else                { Wsrc = Wv; Nrow = N0 - 1024; }

    const float* xrow = X    + (size_t)(M0 + rs) * 768 + seg * 8;
    const float* wrow = Wsrc + (size_t)(Nrow + rs) * 768 + seg * 8;

    // prologue: stage step 0 into buffer 0
    {
        float4 xa = *(const float4*)(xrow);
        float4 xb = *(const float4*)(xrow + 4);
        float4 wa = *(const float4*)(wrow);
        float4 wb = *(const float4*)(wrow + 4);
        uint4 xp, wp;
        xp.x = pk2bf(xa.x, xa.y); xp.y = pk2bf(xa.z, xa.w);
        xp.z = pk2bf(xb.x, xb.y); xp.w = pk2bf(xb.z, xb.w);
        wp.x = pk2bf(wa.x, wa.y); wp.y = pk2bf(wa.z, wa.w);
        wp.z = pk2bf(wb.x, wb.y); wp.w = pk2bf(wb.z, wb.w);
        *(uint4*)&Xs[0][rs][seg * 8]  = xp;
        *(uint4*)&Wsm[0][rs][seg * 8] = wp;
    }
    __syncthreads();

    f32x4 acc[4] = {};
    for (int step = 0; step < 24; ++step) {
        int cur = step & 1;
        float4 xa, xb, wa, wb;
        if (step < 23) {
            int k0 = (step + 1) * 32;
            xa = *(const float4*)(xrow + k0);
            xb = *(const float4*)(xrow + k0 + 4);
            wa = *(const float4*)(wrow + k0);
            wb = *(const float4*)(wrow + k0 + 4);
        }
        bf16x8 a = *(bf16x8*)&Xs[cur][w * 16 + l15][q * 8];
#pragma unroll
        for (int ct = 0; ct < 4; ++ct) {
            bf16x8 bfr = *(bf16x8*)&Wsm[cur][ct * 16 + l15][q * 8];
            acc[ct] = __builtin_amdgcn_mfma_f32_16x16x32_bf16(a, bfr, acc[ct], 0, 0, 0);
        }
        if (step < 23) {
            uint4 xp, wp;
            xp.x = pk2bf(xa.x, xa.y); xp.y = pk2bf(xa.z, xa.w);
            xp.z = pk2bf(xb.x, xb.y); xp.w = pk2bf(xb.z, xb.w);
            wp.x = pk2bf(wa.x, wa.y); wp.y = pk2bf(wa.z, wa.w);
            wp.z = pk2bf(wb.x, wb.y); wp.w = pk2bf(wb.z, wb.w);
            *(uint4*)&Xs[cur ^ 1][rs][seg * 8]  = xp;
            *(uint4*)&Wsm[cur ^ 1][rs][seg * 8] = wp;
        }
        __syncthreads();
    }

    if (N0 < 1024) {
        int isQ = (N0 < 512);
#pragma unroll
        for (int ct = 0; ct < 4; ++ct) {
            float u0 = isQ ? u_bias[N0 + ct * 16 + l15] : 0.f;
            float sc = isQ ? 0.125f : 1.0f;
#pragma unroll
            for (int r = 0; r < 4; ++r)
                Ct[w * 16 + q * 4 + r][ct * 16 + l15] = f2bf((acc[ct][r] + u0) * sc);
        }
        __syncthreads();
        int Nh = isQ ? N0 : (N0 - 512);
        unsigned short* out = isQ ? Qb : Kb;
        size_t base = ((size_t)((M0 >> 10) * 8 + (Nh >> 6)) * 1024 + (M0 & 1023)) * 64;
#pragma unroll
        for (int it = 0; it < 2; ++it) {
            int idx = tid + it * 256;
            int row = idx >> 3, sg = idx & 7;
            *(uint4*)(out + base + (size_t)row * 64 + sg * 8) = *(uint4*)&Ct[row][sg * 8];
        }
    } else {
#pragma unroll
        for (int ct = 0; ct < 4; ++ct) {
            ushort4 pk;
            pk.x = f2bf(acc[ct][0]); pk.y = f2bf(acc[ct][1]);
            pk.z = f2bf(acc[ct][2]); pk.w = f2bf(acc[ct][3]);
            *(ushort4*)&Ct[ct * 16 + l15][w * 16 + q * 4] = pk;   // [d][j]
        }
        __syncthreads();
        size_t base = ((size_t)((M0 >> 10) * 8 + ((N0 - 1024) >> 6))) * 65536;
        int j0 = M0 & 1023;
#pragma unroll
        for (int it = 0; it < 2; ++it) {
            int idx = tid + it * 256;
            int d = idx >> 3, sg = idx & 7;
            *(uint4*)(Vtb + base + (size_t)d * 1024 + j0 + sg * 8) = *(uint4*)&Ct[d][sg * 8];
        }
    }
}

// ---------------------------------------------------------------------------
// out-projection GEMM: 32x64 tiles, grid (12,64) = 768 blocks (3/CU).
// fp32 out [2048][768] = aob[2048][512] @ Wo[768][512]^T + bo
// A = bf16 (ours), B = fp32 Wo converted during staging; double-buffered.
// Waves: mh = w&1 (16 rows), nh = w>>1 (32 cols = 2 ct).
// ---------------------------------------------------------------------------
__global__ __launch_bounds__(256) void gemm_o(
    const unsigned short* __restrict__ X, const float* __restrict__ W,
    const float* __restrict__ bias, float* __restrict__ out)
{
    __shared__ unsigned short Xs[2][32][40];
    __shared__ unsigned short Wsm[2][64][40];
    __shared__ float Ctf[32][72];

    int tid = threadIdx.x;
    int w = tid >> 6, lane = tid & 63, l15 = lane & 15, q = lane >> 4;
    int mh = w & 1, nh = w >> 1;
    int M0 = blockIdx.y * 32, N0 = blockIdx.x * 64;

    int xr = tid >> 3, xseg = tid & 7;    // 32 rows x 8 segs of 4 shorts
    int wr = tid >> 2, wseg = tid & 3;    // 64 rows x 4 segs of 8 floats

    const unsigned short* xrow = X + (size_t)(M0 + xr) * 512 + xseg * 4;
    const float*          wrow = W + (size_t)(N0 + wr) * 512 + wseg * 8;

    {
        ushort4 xv = *(const ushort4*)(xrow);
        float4 wa = *(const float4*)(wrow);
        float4 wb = *(const float4*)(wrow + 4);
        uint4 wp;
        wp.x = pk2bf(wa.x, wa.y); wp.y = pk2bf(wa.z, wa.w);
        wp.z = pk2bf(wb.x, wb.y); wp.w = pk2bf(wb.z, wb.w);
        *(ushort4*)&Xs[0][xr][xseg * 4] = xv;
        *(uint4*)&Wsm[0][wr][wseg * 8]  = wp;
    }
    __syncthreads();

    f32x4 acc[2] = {};
    for (int step = 0; step < 16; ++step) {
        int cur = step & 1;
        ushort4 xv; float4 wa, wb;
        if (step < 15) {
            int k0 = (step + 1) * 32;
            xv = *(const ushort4*)(xrow + k0);
            wa = *(const float4*)(wrow + k0);
            wb = *(const float4*)(wrow + k0 + 4);
        }
        bf16x8 a = *(bf16x8*)&Xs[cur][mh * 16 + l15][q * 8];
#pragma unroll
        for (int ct = 0; ct < 2; ++ct) {
            bf16x8 bfr = *(bf16x8*)&Wsm[cur][nh * 32 + ct * 16 + l15][q * 8];
            acc[ct] = __builtin_amdgcn_mfma_f32_16x16x32_bf16(a, bfr, acc[ct], 0, 0, 0);
        }
        if (step < 15) {
            uint4 wp;
            wp.x = pk2bf(wa.x, wa.y); wp.y = pk2bf(wa.z, wa.w);
            wp.z = pk2bf(wb.x, wb.y); wp.w = pk2bf(wb.z, wb.w);
            *(ushort4*)&Xs[cur ^ 1][xr][xseg * 4] = xv;
            *(uint4*)&Wsm[cur ^ 1][wr][wseg * 8]  = wp;
        }
        __syncthreads();
    }

#pragma unroll
    for (int ct = 0; ct < 2; ++ct) {
        float bv = bias[N0 + nh * 32 + ct * 16 + l15];
#pragma unroll
        for (int r = 0; r < 4; ++r)
            Ctf[mh * 16 + q * 4 + r][nh * 32 + ct * 16 + l15] = acc[ct][r] + bv;
    }
    __syncthreads();
#pragma unroll
    for (int it = 0; it < 2; ++it) {
        int idx = tid + it * 256;
        int row = idx >> 4, sg = idx & 15;
        *(float4*)(out + (size_t)(M0 + row) * 768 + N0 + sg * 4) = *(float4*)&Ctf[row][sg * 4];
    }
}

// ---------------------------------------------------------------------------
// MFMA flash attention with fused qr-bias computation.
// Preamble: stage w_pos[h] fp32->bf16 transposed into LDS; qw = Q'@w_pos^T
//           (2 MFMA/wave); broadcast suffix-scan; biasT in LDS.
// K-loop: 4 waves = 4 j-quarters, fully unrolled, no barriers.
// ---------------------------------------------------------------------------
__global__ __launch_bounds__(256, 4) void attn_mfma(
    const unsigned short* __restrict__ Qbf,   // [bh][i][d] bf16 ((q+u)/8)
    const unsigned short* __restrict__ Kbf,   // [bh][j][d] bf16
    const unsigned short* __restrict__ Vt,    // [bh][d][j] bf16
    const float* __restrict__ w_pos,          // [h][d][n] fp32
    const float* __restrict__ wsfx,           // [h][64]  (vsfx-usfx)/8
    const unsigned char* __restrict__ cls_g,
    unsigned short* __restrict__ ao)          // [b*1024+i][h*64+d] bf16
{
    __shared__ float biasT[16 * 99];
    __shared__ unsigned char cls[2048];
    __shared__ unsigned short Pl[4][16][76];
    union Ovl {
        struct { unsigned short wptS[64][68]; float qwL[16][68]; } pre;
        struct { float Obuf[4][64][17]; float lbuf[4][16]; } post;
    };
    __shared__ Ovl ovl;

    int tid = threadIdx.x;
    int b = blockIdx.z, h = blockIdx.y, bh = b * 8 + h;
    int i0 = blockIdx.x * 16;
    int w = tid >> 6, lane = tid & 63, l15 = lane & 15, q = lane >> 4;

    for (int idx = tid; idx < 512; idx += 256)
        ((unsigned int*)cls)[idx] = ((const unsigned int*)cls_g)[idx];
    {
        const float4* wsrc = (const float4*)(w_pos + h * 4096);
#pragma unroll
        for (int it = 0; it < 4; ++it) {
            int f = tid + it * 256;
            float4 wv = wsrc[f];
            int d = f >> 4, n4 = (f & 15) * 4;
            ovl.pre.wptS[n4 + 0][d] = f2bf(wv.x);
            ovl.pre.wptS[n4 + 1][d] = f2bf(wv.y);
            ovl.pre.wptS[n4 + 2][d] = f2bf(wv.z);
            ovl.pre.wptS[n4 + 3][d] = f2bf(wv.w);
        }
    }

    int ig = i0 + l15;
    const unsigned short* qrow = Qbf + ((size_t)bh * 1024 + ig) * 64;
    bf16x8 qf0 = *(const bf16x8*)(qrow + q * 8);
    bf16x8 qf1 = *(const bf16x8*)(qrow + 32 + q * 8);
    __syncthreads();

    {
        bf16x8 b0 = *(bf16x8*)&ovl.pre.wptS[w * 16 + l15][q * 8];
        bf16x8 b1 = *(bf16x8*)&ovl.pre.wptS[w * 16 + l15][32 + q * 8];
        f32x4 a = {};
        a = __builtin_amdgcn_mfma_f32_16x16x32_bf16(qf0, b0, a, 0, 0, 0);
        a = __builtin_amdgcn_mfma_f32_16x16x32_bf16(qf1, b1, a, 0, 0, 0);
#pragma unroll
        for (int r = 0; r < 4; ++r)
            ovl.pre.qwL[q * 4 + r][w * 16 + l15] = a[r];
    }
    __syncthreads();

    const float* wsh = wsfx + h * 64;
#pragma unroll
    for (int it = 0; it < 4; ++it) {
        int idx = tid + it * 256;
        int il = idx >> 6, n = idx & 63, nn = n & 31, cb = n & 32;
        float run = 0.f, s = 0.f;
#pragma unroll
        for (int c = 31; c >= 0; --c) {
            run += ovl.pre.qwL[il][cb + c];
            if (c == nn) s = run;
        }
        ovl.pre.qwL[il][n] = s + wsh[n];
    }
    __syncthreads();

    for (int idx = tid; idx < 528; idx += 256) {
        int il = idx / 33, c = idx - il * 33;
        float up = 0.f, sp = 0.f;
        if (c < 32) {
            up = ovl.pre.qwL[il][c];
            sp = ovl.pre.qwL[il][32 + c];
        }
        float* bt = biasT + il * 99;
        bt[c]      = up - sp;   // dd < 0
        bt[33 + c] = up;        // dd == 0
        bt[66 + c] = up + sp;   // dd > 0
    }
    __syncthreads();

    const unsigned short* Kbase = Kbf + (size_t)bh * 65536;
    const unsigned short* Vbase = Vt  + (size_t)bh * 65536;
    const float* btrow = biasT + l15 * 99;
    int clsoff = 1023 - ig;

    f32x4 Oacc[4] = {};
    float lsum = 0.f;

#pragma unroll
    for (int jt = 0; jt < 4; ++jt) {
        int jb = w * 256 + jt * 64;
        f32x4 st[4];
#pragma unroll
        for (int ct = 0; ct < 4; ++ct) {
            const unsigned short* krow = Kbase + (size_t)(jb + ct * 16 + l15) * 64;
            bf16x8 ka0 = *(const bf16x8*)(krow + q * 8);
            bf16x8 ka1 = *(const bf16x8*)(krow + 32 + q * 8);
            f32x4 a = {};
            a = __builtin_amdgcn_mfma_f32_16x16x32_bf16(ka0, qf0, a, 0, 0, 0);
            a = __builtin_amdgcn_mfma_f32_16x16x32_bf16(ka1, qf1, a, 0, 0, 0);
            st[ct] = a;
        }
#pragma unroll
        for (int ct = 0; ct < 4; ++ct) {
            int d2b = jb + ct * 16 + q * 4 + clsoff;
            float pv[4];
#pragma unroll
            for (int r = 0; r < 4; ++r) {
                float s = st[ct][r] + btrow[cls[d2b + r]];
                float p = __expf(s);
                lsum += p;
                pv[r] = p;
            }
            ushort4 pk;
            pk.x = f2bf(pv[0]); pk.y = f2bf(pv[1]);
            pk.z = f2bf(pv[2]); pk.w = f2bf(pv[3]);
            *(ushort4*)&Pl[w][l15][ct * 16 + q * 4] = pk;
        }
#pragma unroll
        for (int ks = 0; ks < 2; ++ks) {
            bf16x8 pb = *(const bf16x8*)&Pl[w][l15][ks * 32 + q * 8];
#pragma unroll
            for (int dt = 0; dt < 4; ++dt) {
                bf16x8 va = *(const bf16x8*)(Vbase + (size_t)(dt * 16 + l15) * 1024
                                             + jb + ks * 32 + q * 8);
                Oacc[dt] = __builtin_amdgcn_mfma_f32_16x16x32_bf16(va, pb, Oacc[dt], 0, 0, 0);
            }
        }
    }

    lsum += __shfl_xor(lsum, 16);
    lsum += __shfl_xor(lsum, 32);

    __syncthreads();   // all preamble/K-loop reads done before overlay reuse
#pragma unroll
    for (int dt = 0; dt < 4; ++dt)
#pragma unroll
        for (int r = 0; r < 4; ++r)
            ovl.post.Obuf[w][dt * 16 + q * 4 + r][l15] = Oacc[dt][r];
    if (lane < 16) ovl.post.lbuf[w][l15] = lsum;
    __syncthreads();

    for (int t2 = tid; t2 < 1024; t2 += 256) {
        int il = t2 >> 6, d = t2 & 63;
        float o = ovl.post.Obuf[0][d][il] + ovl.post.Obuf[1][d][il]
                + ovl.post.Obuf[2][d][il] + ovl.post.Obuf[3][d][il];
        float l = ovl.post.lbuf[0][il] + ovl.post.lbuf[1][il]
                + ovl.post.lbuf[2][il] + ovl.post.lbuf[3][il];
        ao[((size_t)(b * 1024 + i0 + il)) * 512 + h * 64 + d] = f2bf(o / l);
    }
}

// ---------------------------------------------------------------------------
extern "C" void kernel_launch(void* const* d_in, const int* in_sizes, int n_in,
                              void* d_out, int out_size, void* d_ws, size_t ws_size,
                              hipStream_t stream)
{
    const float* x      = (const float*)d_in[0];
    const float* Wq     = (const float*)d_in[1];
    const float* Wk     = (const float*)d_in[2];
    const float* Wv     = (const float*)d_in[3];
    const float* Wo     = (const float*)d_in[4];
    const float* bo     = (const float*)d_in[5];
    const float* u_bias = (const float*)d_in[6];
    const float* v_bias = (const float*)d_in[7];
    const float* w_pos  = (const float*)d_in[8];
    float* out = (float*)d_out;

    char* ws = (char*)d_ws;
    unsigned short* Qbf  = (unsigned short*)ws;            ws += 2097152;
    unsigned short* Kbf  = (unsigned short*)ws;            ws += 2097152;
    unsigned short* Vtb  = (unsigned short*)ws;            ws += 2097152;
    unsigned short* aob  = (unsigned short*)ws;            ws += 2097152;
    float*          wsfx = (float*)ws;                     ws += 2048;
    unsigned char*  clsg = (unsigned char*)ws;             ws += 2048;

    gemm_qkv<<<dim3(24, 33), 256, 0, stream>>>(
        x, Wq, Wk, Wv, u_bias, v_bias, w_pos,
        Qbf, Kbf, Vtb, wsfx, clsg);

    attn_mfma<<<dim3(64, 8, 2), 256, 0, stream>>>(
        Qbf, Kbf, Vtb, w_pos, wsfx, clsg, aob);

    gemm_o<<<dim3(12, 64), 256, 0, stream>>>(aob, Wo, bo, out);
}